// Round 5
// baseline (970.797 us; speedup 1.0000x reference)
//
#include <hip/hip_runtime.h>

#define L 2048
#define DIM 1024
#define ROWS 8192     // b*l
#define NSEG 16       // segments per sequence
#define SEG_CHUNKS 8  // chunks per segment
#define SEG_TOK 128   // tokens per segment

typedef __attribute__((ext_vector_type(4))) _Float16 v4h;
typedef __attribute__((ext_vector_type(4))) float v4f;
typedef __attribute__((ext_vector_type(8))) short v8s;

#if defined(__HIP_DEVICE_COMPILE__)
#define MFMA_F16_16x16x16(a, b, c) __builtin_amdgcn_mfma_f32_16x16x16f16((a), (b), (c), 0, 0, 0)
#define MFMA_BF16_16x16x32(a, b, c) __builtin_amdgcn_mfma_f32_16x16x32_bf16((a), (b), (c), 0, 0, 0)
#else
#define MFMA_F16_16x16x16(a, b, c) (c)
#define MFMA_BF16_16x16x32(a, b, c) (c)
#endif

// async global->LDS, 16B/lane; LDS dest = wave-uniform base + lane*16
__device__ inline void gld16(const unsigned short* g, unsigned short* l) {
#if defined(__HIP_DEVICE_COMPILE__)
  __builtin_amdgcn_global_load_lds(
      (__attribute__((address_space(1))) void*)g,
      (__attribute__((address_space(3))) void*)l, 16, 0, 0);
#endif
}

__device__ inline unsigned short f2bf(float f) {
  unsigned int u = __float_as_uint(f);
  unsigned int r = (u + 0x7fffu + ((u >> 16) & 1u)) >> 16;
  return (unsigned short)r;
}
__device__ inline void u2_unpack(const uint2 u, float* f) {  // bf16 x4
  f[0] = __uint_as_float((u.x & 0xffffu) << 16);
  f[1] = __uint_as_float(u.x & 0xffff0000u);
  f[2] = __uint_as_float((u.y & 0xffffu) << 16);
  f[3] = __uint_as_float(u.y & 0xffff0000u);
}
__device__ inline uint4 pack8(const float4 a, const float4 b) {
  uint4 u;
  u.x = (unsigned int)f2bf(a.x) | ((unsigned int)f2bf(a.y) << 16);
  u.y = (unsigned int)f2bf(a.z) | ((unsigned int)f2bf(a.w) << 16);
  u.z = (unsigned int)f2bf(b.x) | ((unsigned int)f2bf(b.y) << 16);
  u.w = (unsigned int)f2bf(b.z) | ((unsigned int)f2bf(b.w) << 16);
  return u;
}
__device__ inline unsigned short f2h_us(float f) {
  _Float16 h = (_Float16)f;
  unsigned short u;
  __builtin_memcpy(&u, &h, 2);
  return u;
}
__device__ inline float h2f_us(unsigned short u) {
  _Float16 h;
  __builtin_memcpy(&h, &u, 2);
  return (float)h;
}
__device__ inline void h4_unpack(const uint2 u, float* f) {  // f16 x4
  f[0] = h2f_us((unsigned short)(u.x & 0xffffu));
  f[1] = h2f_us((unsigned short)(u.x >> 16));
  f[2] = h2f_us((unsigned short)(u.y & 0xffffu));
  f[3] = h2f_us((unsigned short)(u.y >> 16));
}

// ---------------------------------------------------------------------------
// One-shot fp32->bf16: H (2M float4) then Wq,Wk,Wv,Wg (256K float4 each).
// ---------------------------------------------------------------------------
__global__ __launch_bounds__(256) void cvt_all(const float* __restrict__ H,
                                               const float* __restrict__ w0,
                                               const float* __restrict__ w1,
                                               const float* __restrict__ w2,
                                               const float* __restrict__ w3,
                                               unsigned short* __restrict__ Hbf,
                                               unsigned short* __restrict__ Wbf) {
  const int i = blockIdx.x * 256 + threadIdx.x;  // float4 index
  const float* s;
  unsigned short* d;
  int li;
  if (i < 2097152) {
    s = H; d = Hbf; li = i;
  } else {
    const int j = i - 2097152;
    const int w = j >> 18;          // 262144 float4 per weight
    li = j & 262143;
    s = (w == 0) ? w0 : (w == 1) ? w1 : (w == 2) ? w2 : w3;
    d = Wbf + (size_t)w * DIM * DIM;
  }
  const float4 v = ((const float4*)s)[li];
  uint2 u;
  u.x = (unsigned int)f2bf(v.x) | ((unsigned int)f2bf(v.y) << 16);
  u.y = (unsigned int)f2bf(v.z) | ((unsigned int)f2bf(v.w) << 16);
  ((uint2*)d)[li] = u;
}

__global__ __launch_bounds__(256) void cvt_f2b(const float* __restrict__ s,
                                               unsigned short* __restrict__ d) {
  const int i = blockIdx.x * 256 + threadIdx.x;
  const float4 v = ((const float4*)s)[i];
  uint2 u;
  u.x = (unsigned int)f2bf(v.x) | ((unsigned int)f2bf(v.y) << 16);
  u.y = (unsigned int)f2bf(v.z) | ((unsigned int)f2bf(v.w) << 16);
  ((uint2*)d)[i] = u;
}

// ---------------------------------------------------------------------------
// m97-style GEMM: C = A[M,K] @ B[N,K]^T, bf16, BK=64, 128x128 tile,
// global_load_lds w16 staging, XOR-swizzled LDS (0 bank conflicts).
// NOTE (r2): do NOT split the N range — perf depends on the full grid.
// ---------------------------------------------------------------------------
__global__ __launch_bounds__(256) void gemm_a(const unsigned short* __restrict__ A,
                                              const unsigned short* __restrict__ B,
                                              unsigned short* __restrict__ o0,
                                              unsigned short* __restrict__ o1,
                                              unsigned short* __restrict__ o2,
                                              unsigned short* __restrict__ o3) {
  __shared__ __align__(16) unsigned short As[128 * 64];
  __shared__ __align__(16) unsigned short Bs[128 * 64];
  const int tid = threadIdx.x;
  const int bm = blockIdx.y * 128;
  const int bn = blockIdx.x * 128;
  const int wave = tid >> 6;
  const int lane = tid & 63;
  const int m16 = lane & 15;
  const int g = lane >> 4;
  const int wm = (wave >> 1) * 64;
  const int wn = (wave & 1) * 64;
  const int srow8 = lane >> 3;
  const int schk = lane & 7;

  v4f acc[4][4];
#pragma unroll
  for (int i = 0; i < 4; i++)
#pragma unroll
    for (int j = 0; j < 4; j++) acc[i][j] = (v4f){0.f, 0.f, 0.f, 0.f};

  for (int kt = 0; kt < DIM; kt += 64) {
    __syncthreads();
#pragma unroll
    for (int j = 0; j < 4; j++) {
      const int r = wave * 32 + j * 8 + srow8;
      const int cg = schk ^ (r & 7);
      gld16(A + (size_t)(bm + r) * DIM + kt + cg * 8, &As[(wave * 32 + j * 8) * 64]);
      gld16(B + (size_t)(bn + r) * DIM + kt + cg * 8, &Bs[(wave * 32 + j * 8) * 64]);
    }
    __syncthreads();
#pragma unroll
    for (int kh = 0; kh < 2; kh++) {
      v8s af[4], bf[4];
#pragma unroll
      for (int i = 0; i < 4; i++) {
        const int r = wm + i * 16 + m16;
        af[i] = *(const v8s*)&As[r * 64 + (((kh * 4 + g) ^ (r & 7)) * 8)];
      }
#pragma unroll
      for (int j = 0; j < 4; j++) {
        const int r = wn + j * 16 + m16;
        bf[j] = *(const v8s*)&Bs[r * 64 + (((kh * 4 + g) ^ (r & 7)) * 8)];
      }
#pragma unroll
      for (int i = 0; i < 4; i++)
#pragma unroll
        for (int j = 0; j < 4; j++) acc[i][j] = MFMA_BF16_16x16x32(af[i], bf[j], acc[i][j]);
    }
  }

  const int t = bn >> 10;
  const int cb = bn & 1023;
  unsigned short* C = (t == 0) ? o0 : (t == 1) ? o1 : (t == 2) ? o2 : o3;
#pragma unroll
  for (int i = 0; i < 4; i++)
#pragma unroll
    for (int e = 0; e < 4; e++) {
      const size_t row = (size_t)(bm + wm + i * 16 + 4 * g + e);
#pragma unroll
      for (int j = 0; j < 4; j++)
        C[row * DIM + cb + wn + j * 16 + m16] = f2bf(acc[i][j][e]);
    }
}

// ---------------------------------------------------------------------------
// Wo GEMM (fp32 out) — identical structure, separate name for profiling.
// ---------------------------------------------------------------------------
__global__ __launch_bounds__(256) void gemm_w(const unsigned short* __restrict__ A,
                                              const unsigned short* __restrict__ B,
                                              float* __restrict__ C) {
  __shared__ __align__(16) unsigned short As[128 * 64];
  __shared__ __align__(16) unsigned short Bs[128 * 64];
  const int tid = threadIdx.x;
  const int bm = blockIdx.y * 128;
  const int bn = blockIdx.x * 128;
  const int wave = tid >> 6;
  const int lane = tid & 63;
  const int m16 = lane & 15;
  const int g = lane >> 4;
  const int wm = (wave >> 1) * 64;
  const int wn = (wave & 1) * 64;
  const int srow8 = lane >> 3;
  const int schk = lane & 7;

  v4f acc[4][4];
#pragma unroll
  for (int i = 0; i < 4; i++)
#pragma unroll
    for (int j = 0; j < 4; j++) acc[i][j] = (v4f){0.f, 0.f, 0.f, 0.f};

  for (int kt = 0; kt < DIM; kt += 64) {
    __syncthreads();
#pragma unroll
    for (int j = 0; j < 4; j++) {
      const int r = wave * 32 + j * 8 + srow8;
      const int cg = schk ^ (r & 7);
      gld16(A + (size_t)(bm + r) * DIM + kt + cg * 8, &As[(wave * 32 + j * 8) * 64]);
      gld16(B + (size_t)(bn + r) * DIM + kt + cg * 8, &Bs[(wave * 32 + j * 8) * 64]);
    }
    __syncthreads();
#pragma unroll
    for (int kh = 0; kh < 2; kh++) {
      v8s af[4], bf[4];
#pragma unroll
      for (int i = 0; i < 4; i++) {
        const int r = wm + i * 16 + m16;
        af[i] = *(const v8s*)&As[r * 64 + (((kh * 4 + g) ^ (r & 7)) * 8)];
      }
#pragma unroll
      for (int j = 0; j < 4; j++) {
        const int r = wn + j * 16 + m16;
        bf[j] = *(const v8s*)&Bs[r * 64 + (((kh * 4 + g) ^ (r & 7)) * 8)];
      }
#pragma unroll
      for (int i = 0; i < 4; i++)
#pragma unroll
        for (int j = 0; j < 4; j++) acc[i][j] = MFMA_BF16_16x16x32(af[i], bf[j], acc[i][j]);
    }
  }

#pragma unroll
  for (int i = 0; i < 4; i++)
#pragma unroll
    for (int e = 0; e < 4; e++) {
      const size_t row = (size_t)(bm + wm + i * 16 + 4 * g + e);
#pragma unroll
      for (int j = 0; j < 4; j++)
        C[row * DIM + bn + wn + j * 16 + m16] = acc[i][j][e];
    }
}

// ---------------------------------------------------------------------------
// Fallback gate GEMM (A = fp32 H, pack in staging). Used when ws is small.
// ---------------------------------------------------------------------------
__global__ __launch_bounds__(256) void gemm_gate(const float* __restrict__ Af,
                                                 const unsigned short* __restrict__ Bf,
                                                 unsigned short* __restrict__ C) {
  __shared__ __align__(16) unsigned short As[128][40];
  __shared__ __align__(16) unsigned short Bs[128][40];
  const int tid = threadIdx.x;
  const int bm = blockIdx.y * 128;
  const int bn = blockIdx.x * 128;
  const int wave = tid >> 6;
  const int lane = tid & 63;
  const int m16 = lane & 15;
  const int g = lane >> 4;
  const int wm = (wave >> 1) * 64;
  const int wn = (wave & 1) * 64;
  const int lr = tid >> 2;
  const int lc = (tid & 3) * 8;

  v4f acc[4][4];
#pragma unroll
  for (int i = 0; i < 4; i++)
#pragma unroll
    for (int j = 0; j < 4; j++) acc[i][j] = (v4f){0.f, 0.f, 0.f, 0.f};

  auto loadAB = [&](int kt, uint4& a0, uint4& a1, uint4& b0, uint4& b1) {
    const float* p0 = Af + (size_t)(bm + lr) * DIM + lc + kt;
    const float* p1 = Af + (size_t)(bm + 64 + lr) * DIM + lc + kt;
    a0 = pack8(*(const float4*)p0, *(const float4*)(p0 + 4));
    a1 = pack8(*(const float4*)p1, *(const float4*)(p1 + 4));
    b0 = *(const uint4*)(Bf + (size_t)(bn + lr) * DIM + lc + kt);
    b1 = *(const uint4*)(Bf + (size_t)(bn + 64 + lr) * DIM + lc + kt);
  };

  uint4 a0, a1, b0, b1;
  loadAB(0, a0, a1, b0, b1);

  for (int kt = 0; kt < DIM; kt += 32) {
    __syncthreads();
    *(uint4*)&As[lr][lc] = a0;
    *(uint4*)&As[64 + lr][lc] = a1;
    *(uint4*)&Bs[lr][lc] = b0;
    *(uint4*)&Bs[64 + lr][lc] = b1;
    __syncthreads();
    if (kt + 32 < DIM) loadAB(kt + 32, a0, a1, b0, b1);
    v8s af[4], bf[4];
#pragma unroll
    for (int i = 0; i < 4; i++) af[i] = *(const v8s*)&As[wm + i * 16 + m16][g * 8];
#pragma unroll
    for (int j = 0; j < 4; j++) bf[j] = *(const v8s*)&Bs[wn + j * 16 + m16][g * 8];
#pragma unroll
    for (int i = 0; i < 4; i++)
#pragma unroll
      for (int j = 0; j < 4; j++) acc[i][j] = MFMA_BF16_16x16x32(af[i], bf[j], acc[i][j]);
  }

#pragma unroll
  for (int i = 0; i < 4; i++)
#pragma unroll
    for (int e = 0; e < 4; e++) {
      const size_t row = (size_t)(bm + wm + i * 16 + 4 * g + e);
#pragma unroll
      for (int j = 0; j < 4; j++)
        C[row * DIM + bn + wn + j * 16 + m16] = f2bf(acc[i][j][e]);
    }
}

// ---------------------------------------------------------------------------
// Copy 3 pre-segment boundary rows of raw q/k/v linears to a side buffer.
// ---------------------------------------------------------------------------
__global__ __launch_bounds__(256) void copy_side(const unsigned short* __restrict__ Q,
                                                 const unsigned short* __restrict__ K,
                                                 const unsigned short* __restrict__ V,
                                                 unsigned short* __restrict__ sQ,
                                                 unsigned short* __restrict__ sK,
                                                 unsigned short* __restrict__ sV) {
  const int idx = blockIdx.x;
  const int j = idx % 3;
  const int bs = idx / 3;
  const int seg = bs & 15;
  const int b = bs >> 4;
  const int ch = threadIdx.x * 4;
  const size_t so = ((size_t)(bs * 3 + j)) * DIM + ch;
  if (seg == 0) {
    const uint2 z = {0u, 0u};
    *(uint2*)(sQ + so) = z;
    *(uint2*)(sK + so) = z;
    *(uint2*)(sV + so) = z;
  } else {
    const size_t go = ((size_t)(b * L + seg * SEG_TOK - 3 + j)) * DIM + ch;
    *(uint2*)(sQ + so) = *(const uint2*)(Q + go);
    *(uint2*)(sK + so) = *(const uint2*)(K + go);
    *(uint2*)(sV + so) = *(const uint2*)(V + go);
  }
}

// ---------------------------------------------------------------------------
// Phase A: segmented fused conv+SiLU(+L2norm) + local Titans scan from W=0.
// Qw/Vw are the WRITE targets for qc and o (same as Qr/Vr in the real call;
// a dead dummy region in the timing-shadow call). REPS>1 = timing shadow:
// repeats the body with a memory clobber; numerics are garbage but all
// stores go to dead memory.
// ---------------------------------------------------------------------------
template <int REPS>
__global__ __launch_bounds__(256) void scan_seg(unsigned short* Qr,
                                                const unsigned short* Kr,
                                                const unsigned short* Vr,
                                                unsigned short* Qw,
                                                unsigned short* Vw,
                                                const unsigned short* __restrict__ sQ,
                                                const unsigned short* __restrict__ sK,
                                                const unsigned short* __restrict__ sV,
                                                const float* __restrict__ CWq,
                                                const float* __restrict__ CWk,
                                                const float* __restrict__ CWv,
                                                float* __restrict__ D) {
  const int seg = blockIdx.x & 15;
  const int h = (blockIdx.x >> 4) & 15;
  const int b = blockIdx.x >> 8;
  const int tid = threadIdx.x;
  const int lane = tid & 63;
  const int dt = tid >> 6;
  const int m = lane & 15;
  const int g = lane >> 4;
  const int segbase = seg * SEG_TOK;

  __shared__ __align__(16) unsigned short rq[32][68];
  __shared__ __align__(16) unsigned short rk[32][68];
  __shared__ __align__(16) unsigned short rv[32][68];
  __shared__ __align__(16) _Float16 qs[16][72];
  __shared__ __align__(16) _Float16 ks[16][72];
  __shared__ __align__(16) _Float16 kts[64][20];
  __shared__ __align__(16) _Float16 vts[64][20];
  __shared__ __align__(16) _Float16 ot16[16][72];  // o-tile staging (coalesced flush)

  const int srow = tid >> 4;
  const int scol = (tid & 15) * 4;
  const size_t gcol = (size_t)h * 64 + scol;

  float wq[4][4], wk[4][4], wv[4][4];
#pragma unroll
  for (int e = 0; e < 4; e++) {
    const float4 a = *(const float4*)(CWq + (gcol + e) * 4);
    const float4 bw = *(const float4*)(CWk + (gcol + e) * 4);
    const float4 cw = *(const float4*)(CWv + (gcol + e) * 4);
    wq[e][0] = a.x; wq[e][1] = a.y; wq[e][2] = a.z; wq[e][3] = a.w;
    wk[e][0] = bw.x; wk[e][1] = bw.y; wk[e][2] = bw.z; wk[e][3] = bw.w;
    wv[e][0] = cw.x; wv[e][1] = cw.y; wv[e][2] = cw.z; wv[e][3] = cw.w;
  }

  if (tid < 48) {
    const int j = tid >> 4;
    const int sc = (tid & 15) * 4;
    const size_t so = ((size_t)((b * NSEG + seg) * 3 + j)) * DIM + h * 64 + sc;
    const int slot = (29 + j);
    *(uint2*)&rq[slot][sc] = *(const uint2*)(sQ + so);
    *(uint2*)&rk[slot][sc] = *(const uint2*)(sK + so);
    *(uint2*)&rv[slot][sc] = *(const uint2*)(sV + so);
  }

#pragma unroll 1
  for (int rep = 0; rep < REPS; ++rep) {
    if (REPS > 1) asm volatile("" ::: "memory");

    v4f Wf[4];
#pragma unroll
    for (int kt = 0; kt < 4; kt++) Wf[kt] = (v4f){0.f, 0.f, 0.f, 0.f};

    size_t gb = ((size_t)(b * L + segbase + srow)) * DIM + gcol;
    uint2 qg = *(const uint2*)(Qr + gb);
    uint2 kg = *(const uint2*)(Kr + gb);
    uint2 vg = *(const uint2*)(Vr + gb);

    for (int c = 0; c < SEG_CHUNKS; c++) {
      const int t = segbase + c * 16 + srow;
      __syncthreads();
      // coalesced flush of chunk c-1's o tile
      if (c > 0) {
        const size_t po = ((size_t)(b * L + segbase + (c - 1) * 16 + srow)) * DIM + gcol;
        *(uint2*)(Vw + po) = *(const uint2*)&ot16[srow][scol];
      }
      *(uint2*)&rq[t & 31][scol] = qg;
      *(uint2*)&rk[t & 31][scol] = kg;
      *(uint2*)&rv[t & 31][scol] = vg;
      const int cn = (c + 1 < SEG_CHUNKS) ? c + 1 : c;
      const size_t gbn = ((size_t)(b * L + segbase + cn * 16 + srow)) * DIM + gcol;
      const uint2 qn = *(const uint2*)(Qr + gbn);
      const uint2 kn = *(const uint2*)(Kr + gbn);
      const uint2 vn = *(const uint2*)(Vr + gbn);
      __syncthreads();

      float sq[4], sk[4], sv[4];
      {
        float q0[4], q1[4], q2[4], q3[4];
        float k0[4], k1[4], k2[4], k3[4];
        float v0[4], v1[4], v2[4], v3[4];
        u2_unpack(qg, q0);
        u2_unpack(kg, k0);
        u2_unpack(vg, v0);
        u2_unpack(*(const uint2*)&rq[(t - 1) & 31][scol], q1);
        u2_unpack(*(const uint2*)&rk[(t - 1) & 31][scol], k1);
        u2_unpack(*(const uint2*)&rv[(t - 1) & 31][scol], v1);
        u2_unpack(*(const uint2*)&rq[(t - 2) & 31][scol], q2);
        u2_unpack(*(const uint2*)&rk[(t - 2) & 31][scol], k2);
        u2_unpack(*(const uint2*)&rv[(t - 2) & 31][scol], v2);
        u2_unpack(*(const uint2*)&rq[(t - 3) & 31][scol], q3);
        u2_unpack(*(const uint2*)&rk[(t - 3) & 31][scol], k3);
        u2_unpack(*(const uint2*)&rv[(t - 3) & 31][scol], v3);
#pragma unroll
        for (int e = 0; e < 4; e++) {
          const float yq = q0[e] + wq[e][0] * q3[e] + wq[e][1] * q2[e] + wq[e][2] * q1[e] + wq[e][3] * q0[e];
          const float yk = k0[e] + wk[e][0] * k3[e] + wk[e][1] * k2[e] + wk[e][2] * k1[e] + wk[e][3] * k0[e];
          const float yv = v0[e] + wv[e][0] * v3[e] + wv[e][1] * v2[e] + wv[e][2] * v1[e] + wv[e][3] * v0[e];
          sq[e] = yq / (1.f + __expf(-yq));
          sk[e] = yk / (1.f + __expf(-yk));
          sv[e] = yv / (1.f + __expf(-yv));
        }
      }
      float ssq = sq[0] * sq[0] + sq[1] * sq[1] + sq[2] * sq[2] + sq[3] * sq[3];
      float ssk = sk[0] * sk[0] + sk[1] * sk[1] + sk[2] * sk[2] + sk[3] * sk[3];
#pragma unroll
      for (int off = 8; off >= 1; off >>= 1) {
        ssq += __shfl_xor(ssq, off, 16);
        ssk += __shfl_xor(ssk, off, 16);
      }
      const float scq = rsqrtf(ssq + 1e-12f);
      const float sck = rsqrtf(ssk + 1e-12f);

      const v4h qh = {(_Float16)(sq[0] * scq), (_Float16)(sq[1] * scq),
                      (_Float16)(sq[2] * scq), (_Float16)(sq[3] * scq)};
      const v4h kh = {(_Float16)(sk[0] * sck), (_Float16)(sk[1] * sck),
                      (_Float16)(sk[2] * sck), (_Float16)(sk[3] * sck)};
      *(v4h*)&qs[srow][scol] = qh;
      *(v4h*)&ks[srow][scol] = kh;
      kts[scol + 0][srow] = kh[0]; kts[scol + 1][srow] = kh[1];
      kts[scol + 2][srow] = kh[2]; kts[scol + 3][srow] = kh[3];
      vts[scol + 0][srow] = (_Float16)sv[0]; vts[scol + 1][srow] = (_Float16)sv[1];
      vts[scol + 2][srow] = (_Float16)sv[2]; vts[scol + 3][srow] = (_Float16)sv[3];

      uint2 qp;
      __builtin_memcpy(&qp, &qh, 8);
      *(uint2*)(Qw + gb) = qp;  // qc (f16) for the correction pass

      __syncthreads();

      v4h qf[4], kf[4], ktf[4];
#pragma unroll
      for (int kt = 0; kt < 4; kt++) {
        qf[kt] = *(const v4h*)&qs[m][kt * 16 + 4 * g];
        kf[kt] = *(const v4h*)&ks[m][kt * 16 + 4 * g];
        ktf[kt] = *(const v4h*)&kts[kt * 16 + m][4 * g];
      }
      const v4h vf = *(const v4h*)&vts[dt * 16 + m][4 * g];

      v4f kq = {0.f, 0.f, 0.f, 0.f};
#pragma unroll
      for (int kt = 0; kt < 4; kt++) kq = MFMA_F16_16x16x16(kf[kt], qf[kt], kq);

      v4h kqA;
#pragma unroll
      for (int e = 0; e < 4; e++)
        kqA[e] = (4 * g + e <= m) ? (_Float16)kq[e] : (_Float16)0.f;

      v4f of = {0.f, 0.f, 0.f, 0.f};
      of = MFMA_F16_16x16x16(kqA, vf, of);
#pragma unroll
      for (int kt = 0; kt < 4; kt++) {
        v4h Wh;
#pragma unroll
        for (int e = 0; e < 4; e++) Wh[e] = (_Float16)Wf[kt][e];
        of = MFMA_F16_16x16x16(qf[kt], Wh, of);
      }
#pragma unroll
      for (int kt = 0; kt < 4; kt++) Wf[kt] = MFMA_F16_16x16x16(ktf[kt], vf, Wf[kt]);

      // stage o tile into LDS (C-frag positions); flushed coalesced next chunk
#pragma unroll
      for (int e = 0; e < 4; e++) ot16[4 * g + e][dt * 16 + m] = (_Float16)of[e];

      qg = qn; kg = kn; vg = vn; gb = gbn;
    }

    // flush last chunk's o tile
    __syncthreads();
    {
      const size_t po = ((size_t)(b * L + segbase + (SEG_CHUNKS - 1) * 16 + srow)) * DIM + gcol;
      *(uint2*)(Vw + po) = *(const uint2*)&ot16[srow][scol];
    }

    float* Dp = D + ((size_t)((b * 16 + h) * NSEG + seg)) * 4096;
#pragma unroll
    for (int kt = 0; kt < 4; kt++)
#pragma unroll
      for (int e = 0; e < 4; e++)
        Dp[(kt * 16 + 4 * g + e) * 64 + dt * 16 + m] = Wf[kt][e];
  }
}

// ---------------------------------------------------------------------------
// Phase B: exclusive prefix over segments, seeded with W0. 1024 blocks,
// 1 elem/thread: load all 16 segs, prefix in registers, store all.
// ---------------------------------------------------------------------------
__global__ __launch_bounds__(256) void prefix_D(float* __restrict__ D,
                                                const float* __restrict__ W0) {
  const int bh = blockIdx.y;                      // 0..63 (b*16+h)
  const int h = bh & 15;
  const int e = blockIdx.x * 256 + threadIdx.x;   // 0..4095
  float* base = D + (size_t)bh * NSEG * 4096 + e;
  float v[NSEG];
#pragma unroll
  for (int s = 0; s < NSEG; s++) v[s] = base[(size_t)s * 4096];
  float p = W0[(size_t)h * 4096 + e];
#pragma unroll
  for (int s = 0; s < NSEG; s++) {
    const float t = v[s];
    v[s] = p;
    p += t;
  }
#pragma unroll
  for (int s = 0; s < NSEG; s++) base[(size_t)s * 4096] = v[s];
}

// ---------------------------------------------------------------------------
// Phase C fused with epilogue: o_full = o_partial + qc @ P_seg, then
// LayerNorm(dk=64) * gate. Ow is the write target (== Op in the real call;
// dead sB in the timing-shadow call). REPS>1 = timing shadow.
// ---------------------------------------------------------------------------
template <int REPS>
__global__ __launch_bounds__(256) void corr_ln_gate(const unsigned short* __restrict__ Qc,
                                                    const float* __restrict__ P,
                                                    const unsigned short* Op,
                                                    unsigned short* Ow,
                                                    const unsigned short* __restrict__ G,
                                                    const float* __restrict__ gamma,
                                                    const float* __restrict__ beta) {
  const int seg = blockIdx.x & 15;
  const int h = (blockIdx.x >> 4) & 15;
  const int b = blockIdx.x >> 8;
  const int tid = threadIdx.x;
  const int lane = tid & 63;
  const int dt = tid >> 6;
  const int m = lane & 15;
  const int g = lane >> 4;

  __shared__ __align__(16) _Float16 Pt[64][72];
  __shared__ __align__(16) _Float16 qt[16][72];
  __shared__ __align__(16) float ot[16][68];

  const float* Pp = P + ((size_t)((b * 16 + h) * NSEG + seg)) * 4096;
#pragma unroll
  for (int i = 0; i < 16; i++) {
    const int el = tid + i * 256;
    Pt[el & 63][el >> 6] = (_Float16)Pp[el];
  }
  __syncthreads();

  // B-frag of P: pb[kt][e] = P[kt*16+4g+e][dt*16+m]
  v4h pb[4];
#pragma unroll
  for (int kt = 0; kt < 4; kt++) pb[kt] = *(const v4h*)&Pt[dt * 16 + m][kt * 16 + 4 * g];

  const int srow = tid >> 4;
  const int scol = (tid & 15) * 4;
  const float4 gm = *(const float4*)(gamma + scol);
  const float4 bt = *(const float4*)(beta + scol);

#pragma unroll 1
  for (int rep = 0; rep < REPS; ++rep) {
    if (REPS > 1) asm volatile("" ::: "memory");
    for (int rt = 0; rt < 8; rt++) {
      const int row0 = seg * SEG_TOK + rt * 16;
      const size_t gb = ((size_t)(b * L + row0 + srow)) * DIM + h * 64 + scol;
      const uint2 qg = *(const uint2*)(Qc + gb);
      const uint2 og = *(const uint2*)(Op + gb);  // o_partial f16x4, coalesced
      __syncthreads();  // previous iteration done with qt/ot
      *(uint2*)&qt[srow][scol] = qg;
      __syncthreads();
      v4h qf[4];
#pragma unroll
      for (int kt = 0; kt < 4; kt++) qf[kt] = *(const v4h*)&qt[m][kt * 16 + 4 * g];
      v4f corr = {0.f, 0.f, 0.f, 0.f};
#pragma unroll
      for (int kt = 0; kt < 4; kt++) corr = MFMA_F16_16x16x16(qf[kt], pb[kt], corr);
      // corr into LDS (C-layout positions); the o_partial add happens at LN time
#pragma unroll
      for (int e = 0; e < 4; e++) ot[4 * g + e][dt * 16 + m] = corr[e];
      __syncthreads();
      // LN over the 64 head cols of row srow + gate multiply
      float op4[4];
      h4_unpack(og, op4);
      const float4 cv = *(const float4*)&ot[srow][scol];
      const float o0 = cv.x + op4[0], o1 = cv.y + op4[1];
      const float o2 = cv.z + op4[2], o3 = cv.w + op4[3];
      float sum = o0 + o1 + o2 + o3;
#pragma unroll
      for (int off = 8; off >= 1; off >>= 1) sum += __shfl_xor(sum, off, 16);
      const float mu = sum * (1.f / 64.f);
      const float d0 = o0 - mu, d1 = o1 - mu, d2 = o2 - mu, d3 = o3 - mu;
      float vs = d0 * d0 + d1 * d1 + d2 * d2 + d3 * d3;
#pragma unroll
      for (int off = 8; off >= 1; off >>= 1) vs += __shfl_xor(vs, off, 16);
      const float rstd = rsqrtf(vs * (1.f / 64.f) + 1e-5f);
      float gt[4];
      u2_unpack(*(const uint2*)(G + gb), gt);
      float outv[4];
      outv[0] = (d0 * rstd * gm.x + bt.x) * gt[0];
      outv[1] = (d1 * rstd * gm.y + bt.y) * gt[1];
      outv[2] = (d2 * rstd * gm.z + bt.z) * gt[2];
      outv[3] = (d3 * rstd * gm.w + bt.w) * gt[3];
      uint2 u;
      u.x = (unsigned int)f2bf(outv[0]) | ((unsigned int)f2bf(outv[1]) << 16);
      u.y = (unsigned int)f2bf(outv[2]) | ((unsigned int)f2bf(outv[3]) << 16);
      *(uint2*)(Ow + gb) = u;
    }
  }
}

// ---------------------------------------------------------------------------
// BIG path this round includes two TIMING SHADOWS (16x repeat, stores to dead
// memory): scan_seg<16> before the real scan (dummy = d_out lower region,
// fully rewritten by real scan_seg+prefix_D), corr_ln_gate<16> before the
// real corr (dummy = sB, dead after scan_seg). Real path identical to r3.
// ---------------------------------------------------------------------------
extern "C" void kernel_launch(void* const* d_in, const int* in_sizes, int n_in,
                              void* d_out, int out_size, void* d_ws, size_t ws_size,
                              hipStream_t stream) {
  const float* H  = (const float*)d_in[0];
  const float* Wq = (const float*)d_in[1];
  const float* Wk = (const float*)d_in[2];
  const float* Wv = (const float*)d_in[3];
  const float* cq = (const float*)d_in[4];
  const float* ck = (const float*)d_in[5];
  const float* cv = (const float*)d_in[6];
  const float* W0 = (const float*)d_in[7];
  const float* gamma = (const float*)d_in[8];
  const float* beta  = (const float*)d_in[9];
  const float* Wg = (const float*)d_in[10];
  const float* Wo = (const float*)d_in[11];

  const size_t SZ = (size_t)ROWS * DIM;   // 8M elements
  const size_t WSZ = (size_t)DIM * DIM;   // 1M elements
  const size_t SIDE = (size_t)192 * DIM;  // per side tensor
  unsigned short* sA = (unsigned short*)d_ws;
  unsigned short* sB = sA + SZ;
  unsigned short* sC = sB + SZ;

  const bool bigws = ws_size >= (3 * SZ + 4 * WSZ + 3 * SIDE) * 2;

  unsigned short* Hbf = (unsigned short*)d_out;
  float* D = (float*)d_out;  // overlays Hbf after QKV GEMM

  if (bigws) {
    unsigned short* Wbf = sC + SZ;              // ws tail
    unsigned short* side = Wbf + 4 * WSZ;
    unsigned short* gate = Hbf + SZ;            // d_out upper half (bf16)
    unsigned short* dummy = Hbf;                // d_out lower: dead until real scan writes D

    cvt_all<<<12288, 256, 0, stream>>>(H, Wq, Wk, Wv, Wg, Hbf, Wbf);
    gemm_a<<<dim3(32, 64), 256, 0, stream>>>(Hbf, Wbf, sA, sB, sC, gate);
    copy_side<<<192, 256, 0, stream>>>(sA, sB, sC, side, side + SIDE, side + 2 * SIDE);
    // timing shadow: same reads as real scan, stores to dead memory, 16x body
    scan_seg<16><<<1024, 256, 0, stream>>>(sA, sB, sC, dummy, dummy,
                                           side, side + SIDE, side + 2 * SIDE,
                                           cq, ck, cv, D);
    scan_seg<1><<<1024, 256, 0, stream>>>(sA, sB, sC, sA, sC,
                                          side, side + SIDE, side + 2 * SIDE,
                                          cq, ck, cv, D);
    prefix_D<<<dim3(16, 64), 256, 0, stream>>>(D, W0);
    // timing shadow: same reads as real corr, stores to dead sB, 16x body
    corr_ln_gate<16><<<1024, 256, 0, stream>>>(sA, D, sC, sB, gate, gamma, beta);
    corr_ln_gate<1><<<1024, 256, 0, stream>>>(sA, D, sC, sC, gate, gamma, beta);
    cvt_f2b<<<WSZ / 1024, 256, 0, stream>>>(Wo, sA);  // Wo bf16 (qc dead)
    gemm_w<<<dim3(8, 64), 256, 0, stream>>>(sC, sA, (float*)d_out);
  } else {
    unsigned short* Wbf = Hbf + SZ;             // d_out tail
    unsigned short* side = Wbf + 4 * WSZ;

    cvt_all<<<12288, 256, 0, stream>>>(H, Wq, Wk, Wv, Wg, Hbf, Wbf);
    gemm_a<<<dim3(24, 64), 256, 0, stream>>>(Hbf, Wbf, sA, sB, sC, nullptr);
    copy_side<<<192, 256, 0, stream>>>(sA, sB, sC, side, side + SIDE, side + 2 * SIDE);
    scan_seg<1><<<1024, 256, 0, stream>>>(sA, sB, sC, sA, sC,
                                          side, side + SIDE, side + 2 * SIDE,
                                          cq, ck, cv, D);
    gemm_gate<<<dim3(8, 64), 256, 0, stream>>>(H, Wbf + 3 * WSZ, sB);  // gate
    prefix_D<<<dim3(16, 64), 256, 0, stream>>>(D, W0);
    corr_ln_gate<1><<<1024, 256, 0, stream>>>(sA, D, sC, sC, sB, gamma, beta);
    cvt_f2b<<<WSZ / 1024, 256, 0, stream>>>(Wo, sA);
    gemm_w<<<dim3(8, 64), 256, 0, stream>>>(sC, sA, (float*)d_out);
  }
}

// Round 6
// 267.613 us; speedup vs baseline: 3.6276x; 3.6276x over previous
//
#include <hip/hip_runtime.h>

#define L 2048
#define DIM 1024
#define ROWS 8192     // b*l
#define NSEG 16       // segments per sequence
#define SEG_CHUNKS 8  // chunks per segment
#define SEG_TOK 128   // tokens per segment

typedef __attribute__((ext_vector_type(4))) _Float16 v4h;
typedef __attribute__((ext_vector_type(4))) float v4f;
typedef __attribute__((ext_vector_type(8))) short v8s;

#if defined(__HIP_DEVICE_COMPILE__)
#define MFMA_F16_16x16x16(a, b, c) __builtin_amdgcn_mfma_f32_16x16x16f16((a), (b), (c), 0, 0, 0)
#define MFMA_BF16_16x16x32(a, b, c) __builtin_amdgcn_mfma_f32_16x16x32_bf16((a), (b), (c), 0, 0, 0)
#define FRCP(x) __builtin_amdgcn_rcpf(x)
#define FRSQ(x) __builtin_amdgcn_rsqf(x)
#else
#define MFMA_F16_16x16x16(a, b, c) (c)
#define MFMA_BF16_16x16x32(a, b, c) (c)
#define FRCP(x) (1.0f / (x))
#define FRSQ(x) (1.0f / sqrtf(x))
#endif

// async global->LDS, 16B/lane; LDS dest = wave-uniform base + lane*16
__device__ inline void gld16(const unsigned short* g, unsigned short* l) {
#if defined(__HIP_DEVICE_COMPILE__)
  __builtin_amdgcn_global_load_lds(
      (__attribute__((address_space(1))) void*)g,
      (__attribute__((address_space(3))) void*)l, 16, 0, 0);
#endif
}

__device__ inline unsigned short f2bf(float f) {
  unsigned int u = __float_as_uint(f);
  unsigned int r = (u + 0x7fffu + ((u >> 16) & 1u)) >> 16;
  return (unsigned short)r;
}
__device__ inline void u2_unpack(const uint2 u, float* f) {  // bf16 x4
  f[0] = __uint_as_float((u.x & 0xffffu) << 16);
  f[1] = __uint_as_float(u.x & 0xffff0000u);
  f[2] = __uint_as_float((u.y & 0xffffu) << 16);
  f[3] = __uint_as_float(u.y & 0xffff0000u);
}
__device__ inline uint4 pack8(const float4 a, const float4 b) {
  uint4 u;
  u.x = (unsigned int)f2bf(a.x) | ((unsigned int)f2bf(a.y) << 16);
  u.y = (unsigned int)f2bf(a.z) | ((unsigned int)f2bf(a.w) << 16);
  u.z = (unsigned int)f2bf(b.x) | ((unsigned int)f2bf(b.y) << 16);
  u.w = (unsigned int)f2bf(b.z) | ((unsigned int)f2bf(b.w) << 16);
  return u;
}
__device__ inline unsigned short f2h_us(float f) {
  _Float16 h = (_Float16)f;
  unsigned short u;
  __builtin_memcpy(&u, &h, 2);
  return u;
}
__device__ inline float h2f_us(unsigned short u) {
  _Float16 h;
  __builtin_memcpy(&h, &u, 2);
  return (float)h;
}
__device__ inline void h4_unpack(const uint2 u, float* f) {  // f16 x4
  f[0] = h2f_us((unsigned short)(u.x & 0xffffu));
  f[1] = h2f_us((unsigned short)(u.x >> 16));
  f[2] = h2f_us((unsigned short)(u.y & 0xffffu));
  f[3] = h2f_us((unsigned short)(u.y >> 16));
}

// ---------------------------------------------------------------------------
// One-shot fp32->bf16: H (2M float4) then Wq,Wk,Wv,Wg (256K float4 each).
// ---------------------------------------------------------------------------
__global__ __launch_bounds__(256) void cvt_all(const float* __restrict__ H,
                                               const float* __restrict__ w0,
                                               const float* __restrict__ w1,
                                               const float* __restrict__ w2,
                                               const float* __restrict__ w3,
                                               unsigned short* __restrict__ Hbf,
                                               unsigned short* __restrict__ Wbf) {
  const int i = blockIdx.x * 256 + threadIdx.x;  // float4 index
  const float* s;
  unsigned short* d;
  int li;
  if (i < 2097152) {
    s = H; d = Hbf; li = i;
  } else {
    const int j = i - 2097152;
    const int w = j >> 18;          // 262144 float4 per weight
    li = j & 262143;
    s = (w == 0) ? w0 : (w == 1) ? w1 : (w == 2) ? w2 : w3;
    d = Wbf + (size_t)w * DIM * DIM;
  }
  const float4 v = ((const float4*)s)[li];
  uint2 u;
  u.x = (unsigned int)f2bf(v.x) | ((unsigned int)f2bf(v.y) << 16);
  u.y = (unsigned int)f2bf(v.z) | ((unsigned int)f2bf(v.w) << 16);
  ((uint2*)d)[li] = u;
}

__global__ __launch_bounds__(256) void cvt_f2b(const float* __restrict__ s,
                                               unsigned short* __restrict__ d) {
  const int i = blockIdx.x * 256 + threadIdx.x;
  const float4 v = ((const float4*)s)[i];
  uint2 u;
  u.x = (unsigned int)f2bf(v.x) | ((unsigned int)f2bf(v.y) << 16);
  u.y = (unsigned int)f2bf(v.z) | ((unsigned int)f2bf(v.w) << 16);
  ((uint2*)d)[i] = u;
}

// ---------------------------------------------------------------------------
// m97-style GEMM: C = A[M,K] @ B[N,K]^T, bf16, BK=64, 128x128 tile,
// global_load_lds w16 staging, XOR-swizzled LDS (0 bank conflicts).
// NOTE (r2): do NOT split the N range — perf depends on the full grid.
// r6: side-row fold — rows with (row&2047)%128 >= 125 (feeding segment s+1)
// are also written to the side buffer during the C-store, replacing the
// copy_side kernel. side layout: ((b*16+seg)*3 + j)*DIM + col, tensor-major
// blocks of SIDE elems (q,k,v for t=0,1,2).
// ---------------------------------------------------------------------------
#define SIDE_ELEMS ((size_t)192 * DIM)
__global__ __launch_bounds__(256) void gemm_a(const unsigned short* __restrict__ A,
                                              const unsigned short* __restrict__ B,
                                              unsigned short* __restrict__ o0,
                                              unsigned short* __restrict__ o1,
                                              unsigned short* __restrict__ o2,
                                              unsigned short* __restrict__ o3,
                                              unsigned short* __restrict__ side) {
  __shared__ __align__(16) unsigned short As[128 * 64];
  __shared__ __align__(16) unsigned short Bs[128 * 64];
  const int tid = threadIdx.x;
  const int bm = blockIdx.y * 128;
  const int bn = blockIdx.x * 128;
  const int wave = tid >> 6;
  const int lane = tid & 63;
  const int m16 = lane & 15;
  const int g = lane >> 4;
  const int wm = (wave >> 1) * 64;
  const int wn = (wave & 1) * 64;
  const int srow8 = lane >> 3;
  const int schk = lane & 7;

  v4f acc[4][4];
#pragma unroll
  for (int i = 0; i < 4; i++)
#pragma unroll
    for (int j = 0; j < 4; j++) acc[i][j] = (v4f){0.f, 0.f, 0.f, 0.f};

  for (int kt = 0; kt < DIM; kt += 64) {
    __syncthreads();
#pragma unroll
    for (int j = 0; j < 4; j++) {
      const int r = wave * 32 + j * 8 + srow8;
      const int cg = schk ^ (r & 7);
      gld16(A + (size_t)(bm + r) * DIM + kt + cg * 8, &As[(wave * 32 + j * 8) * 64]);
      gld16(B + (size_t)(bn + r) * DIM + kt + cg * 8, &Bs[(wave * 32 + j * 8) * 64]);
    }
    __syncthreads();
#pragma unroll
    for (int kh = 0; kh < 2; kh++) {
      v8s af[4], bf[4];
#pragma unroll
      for (int i = 0; i < 4; i++) {
        const int r = wm + i * 16 + m16;
        af[i] = *(const v8s*)&As[r * 64 + (((kh * 4 + g) ^ (r & 7)) * 8)];
      }
#pragma unroll
      for (int j = 0; j < 4; j++) {
        const int r = wn + j * 16 + m16;
        bf[j] = *(const v8s*)&Bs[r * 64 + (((kh * 4 + g) ^ (r & 7)) * 8)];
      }
#pragma unroll
      for (int i = 0; i < 4; i++)
#pragma unroll
        for (int j = 0; j < 4; j++) acc[i][j] = MFMA_BF16_16x16x32(af[i], bf[j], acc[i][j]);
    }
  }

  const int t = bn >> 10;
  const int cb = bn & 1023;
  unsigned short* C = (t == 0) ? o0 : (t == 1) ? o1 : (t == 2) ? o2 : o3;
#pragma unroll
  for (int i = 0; i < 4; i++)
#pragma unroll
    for (int e = 0; e < 4; e++) {
      const size_t row = (size_t)(bm + wm + i * 16 + 4 * g + e);
      const int brow = (int)(row & (L - 1));
      const int p = brow & 127;
      const bool do_side = (t < 3) && (p >= 125) && (brow < 1920) && (side != nullptr);
      size_t soff = 0;
      if (do_side) {
        const int bb = (int)(row >> 11);
        const int st = (brow >> 7) + 1;
        const int js = p - 125;
        soff = (size_t)t * SIDE_ELEMS + ((size_t)((bb * 16 + st) * 3 + js)) * DIM;
      }
#pragma unroll
      for (int j = 0; j < 4; j++) {
        const int col = cb + wn + j * 16 + m16;
        const unsigned short val = f2bf(acc[i][j][e]);
        C[row * DIM + col] = val;
        if (do_side) side[soff + col] = val;
      }
    }
}

// ---------------------------------------------------------------------------
// Wo GEMM (fp32 out), 128x64 tiles -> grid (16,64)=1024 blocks (r5: the 512-
// block 128x128 variant is starved per the r2 grid-size lesson).
// ---------------------------------------------------------------------------
__global__ __launch_bounds__(256) void gemm_w(const unsigned short* __restrict__ A,
                                              const unsigned short* __restrict__ B,
                                              float* __restrict__ C) {
  __shared__ __align__(16) unsigned short As[128 * 64];
  __shared__ __align__(16) unsigned short Bs[64 * 64];
  const int tid = threadIdx.x;
  const int bm = blockIdx.y * 128;
  const int bn = blockIdx.x * 64;
  const int wave = tid >> 6;
  const int lane = tid & 63;
  const int m16 = lane & 15;
  const int g = lane >> 4;
  const int wm = (wave >> 1) * 64;
  const int wn = (wave & 1) * 32;
  const int srow8 = lane >> 3;
  const int schk = lane & 7;

  v4f acc[4][2];
#pragma unroll
  for (int i = 0; i < 4; i++)
#pragma unroll
    for (int j = 0; j < 2; j++) acc[i][j] = (v4f){0.f, 0.f, 0.f, 0.f};

  for (int kt = 0; kt < DIM; kt += 64) {
    __syncthreads();
#pragma unroll
    for (int j = 0; j < 4; j++) {
      const int r = wave * 32 + j * 8 + srow8;
      const int cg = schk ^ (r & 7);
      gld16(A + (size_t)(bm + r) * DIM + kt + cg * 8, &As[(wave * 32 + j * 8) * 64]);
    }
#pragma unroll
    for (int j = 0; j < 2; j++) {
      const int rl = wave * 16 + j * 8;
      const int r = rl + srow8;
      const int cg = schk ^ (r & 7);
      gld16(B + (size_t)(bn + r) * DIM + kt + cg * 8, &Bs[rl * 64]);
    }
    __syncthreads();
#pragma unroll
    for (int kh = 0; kh < 2; kh++) {
      v8s af[4], bf[2];
#pragma unroll
      for (int i = 0; i < 4; i++) {
        const int r = wm + i * 16 + m16;
        af[i] = *(const v8s*)&As[r * 64 + (((kh * 4 + g) ^ (r & 7)) * 8)];
      }
#pragma unroll
      for (int j = 0; j < 2; j++) {
        const int r = wn + j * 16 + m16;
        bf[j] = *(const v8s*)&Bs[r * 64 + (((kh * 4 + g) ^ (r & 7)) * 8)];
      }
#pragma unroll
      for (int i = 0; i < 4; i++)
#pragma unroll
        for (int j = 0; j < 2; j++) acc[i][j] = MFMA_BF16_16x16x32(af[i], bf[j], acc[i][j]);
    }
  }

#pragma unroll
  for (int i = 0; i < 4; i++)
#pragma unroll
    for (int e = 0; e < 4; e++) {
      const size_t row = (size_t)(bm + wm + i * 16 + 4 * g + e);
#pragma unroll
      for (int j = 0; j < 2; j++)
        C[row * DIM + bn + wn + j * 16 + m16] = acc[i][j][e];
    }
}

// ---------------------------------------------------------------------------
// Fallback gate GEMM (A = fp32 H, pack in staging). Used when ws is small.
// ---------------------------------------------------------------------------
__global__ __launch_bounds__(256) void gemm_gate(const float* __restrict__ Af,
                                                 const unsigned short* __restrict__ Bf,
                                                 unsigned short* __restrict__ C) {
  __shared__ __align__(16) unsigned short As[128][40];
  __shared__ __align__(16) unsigned short Bs[128][40];
  const int tid = threadIdx.x;
  const int bm = blockIdx.y * 128;
  const int bn = blockIdx.x * 128;
  const int wave = tid >> 6;
  const int lane = tid & 63;
  const int m16 = lane & 15;
  const int g = lane >> 4;
  const int wm = (wave >> 1) * 64;
  const int wn = (wave & 1) * 64;
  const int lr = tid >> 2;
  const int lc = (tid & 3) * 8;

  v4f acc[4][4];
#pragma unroll
  for (int i = 0; i < 4; i++)
#pragma unroll
    for (int j = 0; j < 4; j++) acc[i][j] = (v4f){0.f, 0.f, 0.f, 0.f};

  auto loadAB = [&](int kt, uint4& a0, uint4& a1, uint4& b0, uint4& b1) {
    const float* p0 = Af + (size_t)(bm + lr) * DIM + lc + kt;
    const float* p1 = Af + (size_t)(bm + 64 + lr) * DIM + lc + kt;
    a0 = pack8(*(const float4*)p0, *(const float4*)(p0 + 4));
    a1 = pack8(*(const float4*)p1, *(const float4*)(p1 + 4));
    b0 = *(const uint4*)(Bf + (size_t)(bn + lr) * DIM + lc + kt);
    b1 = *(const uint4*)(Bf + (size_t)(bn + 64 + lr) * DIM + lc + kt);
  };

  uint4 a0, a1, b0, b1;
  loadAB(0, a0, a1, b0, b1);

  for (int kt = 0; kt < DIM; kt += 32) {
    __syncthreads();
    *(uint4*)&As[lr][lc] = a0;
    *(uint4*)&As[64 + lr][lc] = a1;
    *(uint4*)&Bs[lr][lc] = b0;
    *(uint4*)&Bs[64 + lr][lc] = b1;
    __syncthreads();
    if (kt + 32 < DIM) loadAB(kt + 32, a0, a1, b0, b1);
    v8s af[4], bf[4];
#pragma unroll
    for (int i = 0; i < 4; i++) af[i] = *(const v8s*)&As[wm + i * 16 + m16][g * 8];
#pragma unroll
    for (int j = 0; j < 4; j++) bf[j] = *(const v8s*)&Bs[wn + j * 16 + m16][g * 8];
#pragma unroll
    for (int i = 0; i < 4; i++)
#pragma unroll
      for (int j = 0; j < 4; j++) acc[i][j] = MFMA_BF16_16x16x32(af[i], bf[j], acc[i][j]);
  }

#pragma unroll
  for (int i = 0; i < 4; i++)
#pragma unroll
    for (int e = 0; e < 4; e++) {
      const size_t row = (size_t)(bm + wm + i * 16 + 4 * g + e);
#pragma unroll
      for (int j = 0; j < 4; j++)
        C[row * DIM + bn + wn + j * 16 + m16] = f2bf(acc[i][j][e]);
    }
}

// ---------------------------------------------------------------------------
// Phase A: segmented fused conv+SiLU(+L2norm) + local Titans scan from W=0.
// r6: SiLU uses v_rcp (y*rcp(1+exp(-y))) instead of full-precision divide —
// the f32 div sequence (~10 VALU ops) was ~1/3 of this kernel's VALU work
// (r5 shadow: VALUBusy 62.7%, MfmaUtil 7.9% -> VALU-bound). L2norm uses
// v_rsq. seg==0 side slots are zero-filled here (copy_side removed).
// ---------------------------------------------------------------------------
__global__ __launch_bounds__(256) void scan_seg(unsigned short* Qr,
                                                const unsigned short* Kr,
                                                const unsigned short* Vr,
                                                unsigned short* Qw,
                                                unsigned short* Vw,
                                                const unsigned short* __restrict__ sQ,
                                                const unsigned short* __restrict__ sK,
                                                const unsigned short* __restrict__ sV,
                                                const float* __restrict__ CWq,
                                                const float* __restrict__ CWk,
                                                const float* __restrict__ CWv,
                                                float* __restrict__ D) {
  const int seg = blockIdx.x & 15;
  const int h = (blockIdx.x >> 4) & 15;
  const int b = blockIdx.x >> 8;
  const int tid = threadIdx.x;
  const int lane = tid & 63;
  const int dt = tid >> 6;
  const int m = lane & 15;
  const int g = lane >> 4;
  const int segbase = seg * SEG_TOK;

  __shared__ __align__(16) unsigned short rq[32][68];
  __shared__ __align__(16) unsigned short rk[32][68];
  __shared__ __align__(16) unsigned short rv[32][68];
  __shared__ __align__(16) _Float16 qs[16][72];
  __shared__ __align__(16) _Float16 ks[16][72];
  __shared__ __align__(16) _Float16 kts[64][20];
  __shared__ __align__(16) _Float16 vts[64][20];
  __shared__ __align__(16) _Float16 ot16[16][72];  // o-tile staging (coalesced flush)

  v4f Wf[4];
#pragma unroll
  for (int kt = 0; kt < 4; kt++) Wf[kt] = (v4f){0.f, 0.f, 0.f, 0.f};

  const int srow = tid >> 4;
  const int scol = (tid & 15) * 4;
  const size_t gcol = (size_t)h * 64 + scol;

  float wq[4][4], wk[4][4], wv[4][4];
#pragma unroll
  for (int e = 0; e < 4; e++) {
    const float4 a = *(const float4*)(CWq + (gcol + e) * 4);
    const float4 bw = *(const float4*)(CWk + (gcol + e) * 4);
    const float4 cw = *(const float4*)(CWv + (gcol + e) * 4);
    wq[e][0] = a.x; wq[e][1] = a.y; wq[e][2] = a.z; wq[e][3] = a.w;
    wk[e][0] = bw.x; wk[e][1] = bw.y; wk[e][2] = bw.z; wk[e][3] = bw.w;
    wv[e][0] = cw.x; wv[e][1] = cw.y; wv[e][2] = cw.z; wv[e][3] = cw.w;
  }

  if (tid < 48) {
    const int j = tid >> 4;
    const int sc = (tid & 15) * 4;
    const int slot = (29 + j);
    if (seg == 0) {
      const uint2 z = {0u, 0u};
      *(uint2*)&rq[slot][sc] = z;
      *(uint2*)&rk[slot][sc] = z;
      *(uint2*)&rv[slot][sc] = z;
    } else {
      const size_t so = ((size_t)((b * NSEG + seg) * 3 + j)) * DIM + h * 64 + sc;
      *(uint2*)&rq[slot][sc] = *(const uint2*)(sQ + so);
      *(uint2*)&rk[slot][sc] = *(const uint2*)(sK + so);
      *(uint2*)&rv[slot][sc] = *(const uint2*)(sV + so);
    }
  }

  size_t gb = ((size_t)(b * L + segbase + srow)) * DIM + gcol;
  uint2 qg = *(const uint2*)(Qr + gb);
  uint2 kg = *(const uint2*)(Kr + gb);
  uint2 vg = *(const uint2*)(Vr + gb);

  for (int c = 0; c < SEG_CHUNKS; c++) {
    const int t = segbase + c * 16 + srow;
    __syncthreads();
    // coalesced flush of chunk c-1's o tile
    if (c > 0) {
      const size_t po = ((size_t)(b * L + segbase + (c - 1) * 16 + srow)) * DIM + gcol;
      *(uint2*)(Vw + po) = *(const uint2*)&ot16[srow][scol];
    }
    *(uint2*)&rq[t & 31][scol] = qg;
    *(uint2*)&rk[t & 31][scol] = kg;
    *(uint2*)&rv[t & 31][scol] = vg;
    const int cn = (c + 1 < SEG_CHUNKS) ? c + 1 : c;
    const size_t gbn = ((size_t)(b * L + segbase + cn * 16 + srow)) * DIM + gcol;
    const uint2 qn = *(const uint2*)(Qr + gbn);
    const uint2 kn = *(const uint2*)(Kr + gbn);
    const uint2 vn = *(const uint2*)(Vr + gbn);
    __syncthreads();

    float sq[4], sk[4], sv[4];
    {
      float q0[4], q1[4], q2[4], q3[4];
      float k0[4], k1[4], k2[4], k3[4];
      float v0[4], v1[4], v2[4], v3[4];
      u2_unpack(qg, q0);
      u2_unpack(kg, k0);
      u2_unpack(vg, v0);
      u2_unpack(*(const uint2*)&rq[(t - 1) & 31][scol], q1);
      u2_unpack(*(const uint2*)&rk[(t - 1) & 31][scol], k1);
      u2_unpack(*(const uint2*)&rv[(t - 1) & 31][scol], v1);
      u2_unpack(*(const uint2*)&rq[(t - 2) & 31][scol], q2);
      u2_unpack(*(const uint2*)&rk[(t - 2) & 31][scol], k2);
      u2_unpack(*(const uint2*)&rv[(t - 2) & 31][scol], v2);
      u2_unpack(*(const uint2*)&rq[(t - 3) & 31][scol], q3);
      u2_unpack(*(const uint2*)&rk[(t - 3) & 31][scol], k3);
      u2_unpack(*(const uint2*)&rv[(t - 3) & 31][scol], v3);
#pragma unroll
      for (int e = 0; e < 4; e++) {
        const float yq = q0[e] + wq[e][0] * q3[e] + wq[e][1] * q2[e] + wq[e][2] * q1[e] + wq[e][3] * q0[e];
        const float yk = k0[e] + wk[e][0] * k3[e] + wk[e][1] * k2[e] + wk[e][2] * k1[e] + wk[e][3] * k0[e];
        const float yv = v0[e] + wv[e][0] * v3[e] + wv[e][1] * v2[e] + wv[e][2] * v1[e] + wv[e][3] * v0[e];
        // silu via v_rcp (1-ulp; output is f16 -> harmless) instead of f32 div
        sq[e] = yq * FRCP(1.f + __expf(-yq));
        sk[e] = yk * FRCP(1.f + __expf(-yk));
        sv[e] = yv * FRCP(1.f + __expf(-yv));
      }
    }
    float ssq = sq[0] * sq[0] + sq[1] * sq[1] + sq[2] * sq[2] + sq[3] * sq[3];
    float ssk = sk[0] * sk[0] + sk[1] * sk[1] + sk[2] * sk[2] + sk[3] * sk[3];
#pragma unroll
    for (int off = 8; off >= 1; off >>= 1) {
      ssq += __shfl_xor(ssq, off, 16);
      ssk += __shfl_xor(ssk, off, 16);
    }
    const float scq = FRSQ(ssq + 1e-12f);
    const float sck = FRSQ(ssk + 1e-12f);

    const v4h qh = {(_Float16)(sq[0] * scq), (_Float16)(sq[1] * scq),
                    (_Float16)(sq[2] * scq), (_Float16)(sq[3] * scq)};
    const v4h kh = {(_Float16)(sk[0] * sck), (_Float16)(sk[1] * sck),
                    (_Float16)(sk[2] * sck), (_Float16)(sk[3] * sck)};
    *(v4h*)&qs[srow][scol] = qh;
    *(v4h*)&ks[srow][scol] = kh;
    kts[scol + 0][srow] = kh[0]; kts[scol + 1][srow] = kh[1];
    kts[scol + 2][srow] = kh[2]; kts[scol + 3][srow] = kh[3];
    vts[scol + 0][srow] = (_Float16)sv[0]; vts[scol + 1][srow] = (_Float16)sv[1];
    vts[scol + 2][srow] = (_Float16)sv[2]; vts[scol + 3][srow] = (_Float16)sv[3];

    uint2 qp;
    __builtin_memcpy(&qp, &qh, 8);
    *(uint2*)(Qw + gb) = qp;  // qc (f16) for the correction pass

    __syncthreads();

    v4h qf[4], kf[4], ktf[4];
#pragma unroll
    for (int kt = 0; kt < 4; kt++) {
      qf[kt] = *(const v4h*)&qs[m][kt * 16 + 4 * g];
      kf[kt] = *(const v4h*)&ks[m][kt * 16 + 4 * g];
      ktf[kt] = *(const v4h*)&kts[kt * 16 + m][4 * g];
    }
    const v4h vf = *(const v4h*)&vts[dt * 16 + m][4 * g];

    v4f kq = {0.f, 0.f, 0.f, 0.f};
#pragma unroll
    for (int kt = 0; kt < 4; kt++) kq = MFMA_F16_16x16x16(kf[kt], qf[kt], kq);

    v4h kqA;
#pragma unroll
    for (int e = 0; e < 4; e++)
      kqA[e] = (4 * g + e <= m) ? (_Float16)kq[e] : (_Float16)0.f;

    v4f of = {0.f, 0.f, 0.f, 0.f};
    of = MFMA_F16_16x16x16(kqA, vf, of);
#pragma unroll
    for (int kt = 0; kt < 4; kt++) {
      v4h Wh;
#pragma unroll
      for (int e = 0; e < 4; e++) Wh[e] = (_Float16)Wf[kt][e];
      of = MFMA_F16_16x16x16(qf[kt], Wh, of);
    }
#pragma unroll
    for (int kt = 0; kt < 4; kt++) Wf[kt] = MFMA_F16_16x16x16(ktf[kt], vf, Wf[kt]);

    // stage o tile into LDS (C-frag positions); flushed coalesced next chunk
#pragma unroll
    for (int e = 0; e < 4; e++) ot16[4 * g + e][dt * 16 + m] = (_Float16)of[e];

    qg = qn; kg = kn; vg = vn; gb = gbn;
  }

  // flush last chunk's o tile
  __syncthreads();
  {
    const size_t po = ((size_t)(b * L + segbase + (SEG_CHUNKS - 1) * 16 + srow)) * DIM + gcol;
    *(uint2*)(Vw + po) = *(const uint2*)&ot16[srow][scol];
  }

  float* Dp = D + ((size_t)((b * 16 + h) * NSEG + seg)) * 4096;
#pragma unroll
  for (int kt = 0; kt < 4; kt++)
#pragma unroll
    for (int e = 0; e < 4; e++)
      Dp[(kt * 16 + 4 * g + e) * 64 + dt * 16 + m] = Wf[kt][e];
}

// ---------------------------------------------------------------------------
// Phase B: exclusive prefix over segments, seeded with W0. 1024 blocks,
// 1 elem/thread: load all 16 segs, prefix in registers, store all.
// ---------------------------------------------------------------------------
__global__ __launch_bounds__(256) void prefix_D(float* __restrict__ D,
                                                const float* __restrict__ W0) {
  const int bh = blockIdx.y;                      // 0..63 (b*16+h)
  const int h = bh & 15;
  const int e = blockIdx.x * 256 + threadIdx.x;   // 0..4095
  float* base = D + (size_t)bh * NSEG * 4096 + e;
  float v[NSEG];
#pragma unroll
  for (int s = 0; s < NSEG; s++) v[s] = base[(size_t)s * 4096];
  float p = W0[(size_t)h * 4096 + e];
#pragma unroll
  for (int s = 0; s < NSEG; s++) {
    const float t = v[s];
    v[s] = p;
    p += t;
  }
#pragma unroll
  for (int s = 0; s < NSEG; s++) base[(size_t)s * 4096] = v[s];
}

// ---------------------------------------------------------------------------
// Phase C fused with epilogue: o_full = o_partial + qc @ P_seg, then
// LayerNorm(dk=64) * gate, bf16 out (Ow == Op here).
// ---------------------------------------------------------------------------
__global__ __launch_bounds__(256) void corr_ln_gate(const unsigned short* __restrict__ Qc,
                                                    const float* __restrict__ P,
                                                    const unsigned short* Op,
                                                    unsigned short* Ow,
                                                    const unsigned short* __restrict__ G,
                                                    const float* __restrict__ gamma,
                                                    const float* __restrict__ beta) {
  const int seg = blockIdx.x & 15;
  const int h = (blockIdx.x >> 4) & 15;
  const int b = blockIdx.x >> 8;
  const int tid = threadIdx.x;
  const int lane = tid & 63;
  const int dt = tid >> 6;
  const int m = lane & 15;
  const int g = lane >> 4;

  __shared__ __align__(16) _Float16 Pt[64][72];
  __shared__ __align__(16) _Float16 qt[16][72];
  __shared__ __align__(16) float ot[16][68];

  const float* Pp = P + ((size_t)((b * 16 + h) * NSEG + seg)) * 4096;
#pragma unroll
  for (int i = 0; i < 16; i++) {
    const int el = tid + i * 256;
    Pt[el & 63][el >> 6] = (_Float16)Pp[el];
  }
  __syncthreads();

  // B-frag of P: pb[kt][e] = P[kt*16+4g+e][dt*16+m]
  v4h pb[4];
#pragma unroll
  for (int kt = 0; kt < 4; kt++) pb[kt] = *(const v4h*)&Pt[dt * 16 + m][kt * 16 + 4 * g];

  const int srow = tid >> 4;
  const int scol = (tid & 15) * 4;
  const float4 gm = *(const float4*)(gamma + scol);
  const float4 bt = *(const float4*)(beta + scol);

  for (int rt = 0; rt < 8; rt++) {
    const int row0 = seg * SEG_TOK + rt * 16;
    const size_t gb = ((size_t)(b * L + row0 + srow)) * DIM + h * 64 + scol;
    const uint2 qg = *(const uint2*)(Qc + gb);
    const uint2 og = *(const uint2*)(Op + gb);  // o_partial f16x4, coalesced
    __syncthreads();  // previous iteration done with qt/ot
    *(uint2*)&qt[srow][scol] = qg;
    __syncthreads();
    v4h qf[4];
#pragma unroll
    for (int kt = 0; kt < 4; kt++) qf[kt] = *(const v4h*)&qt[m][kt * 16 + 4 * g];
    v4f corr = {0.f, 0.f, 0.f, 0.f};
#pragma unroll
    for (int kt = 0; kt < 4; kt++) corr = MFMA_F16_16x16x16(qf[kt], pb[kt], corr);
    // corr into LDS (C-layout positions); the o_partial add happens at LN time
#pragma unroll
    for (int e = 0; e < 4; e++) ot[4 * g + e][dt * 16 + m] = corr[e];
    __syncthreads();
    // LN over the 64 head cols of row srow + gate multiply
    float op4[4];
    h4_unpack(og, op4);
    const float4 cv = *(const float4*)&ot[srow][scol];
    const float o0 = cv.x + op4[0], o1 = cv.y + op4[1];
    const float o2 = cv.z + op4[2], o3 = cv.w + op4[3];
    float sum = o0 + o1 + o2 + o3;
#pragma unroll
    for (int off = 8; off >= 1; off >>= 1) sum += __shfl_xor(sum, off, 16);
    const float mu = sum * (1.f / 64.f);
    const float d0 = o0 - mu, d1 = o1 - mu, d2 = o2 - mu, d3 = o3 - mu;
    float vs = d0 * d0 + d1 * d1 + d2 * d2 + d3 * d3;
#pragma unroll
    for (int off = 8; off >= 1; off >>= 1) vs += __shfl_xor(vs, off, 16);
    const float rstd = rsqrtf(vs * (1.f / 64.f) + 1e-5f);
    float gt[4];
    u2_unpack(*(const uint2*)(G + gb), gt);
    float outv[4];
    outv[0] = (d0 * rstd * gm.x + bt.x) * gt[0];
    outv[1] = (d1 * rstd * gm.y + bt.y) * gt[1];
    outv[2] = (d2 * rstd * gm.z + bt.z) * gt[2];
    outv[3] = (d3 * rstd * gm.w + bt.w) * gt[3];
    uint2 u;
    u.x = (unsigned int)f2bf(outv[0]) | ((unsigned int)f2bf(outv[1]) << 16);
    u.y = (unsigned int)f2bf(outv[2]) | ((unsigned int)f2bf(outv[3]) << 16);
    *(uint2*)(Ow + gb) = u;
  }
}

// ---------------------------------------------------------------------------
// BIG (ws >= 59.9 MB): ws = sA,sB,sC,Wbf(4),side; d_out = Hbf->D | gate(bf16).
// copy_side is gone: gemm_a writes side rows in its epilogue; scan_seg
// zero-fills seg==0. SMALL path analogous.
// ---------------------------------------------------------------------------
extern "C" void kernel_launch(void* const* d_in, const int* in_sizes, int n_in,
                              void* d_out, int out_size, void* d_ws, size_t ws_size,
                              hipStream_t stream) {
  const float* H  = (const float*)d_in[0];
  const float* Wq = (const float*)d_in[1];
  const float* Wk = (const float*)d_in[2];
  const float* Wv = (const float*)d_in[3];
  const float* cq = (const float*)d_in[4];
  const float* ck = (const float*)d_in[5];
  const float* cv = (const float*)d_in[6];
  const float* W0 = (const float*)d_in[7];
  const float* gamma = (const float*)d_in[8];
  const float* beta  = (const float*)d_in[9];
  const float* Wg = (const float*)d_in[10];
  const float* Wo = (const float*)d_in[11];

  const size_t SZ = (size_t)ROWS * DIM;   // 8M elements
  const size_t WSZ = (size_t)DIM * DIM;   // 1M elements
  const size_t SIDE = SIDE_ELEMS;         // per side tensor
  unsigned short* sA = (unsigned short*)d_ws;
  unsigned short* sB = sA + SZ;
  unsigned short* sC = sB + SZ;

  const bool bigws = ws_size >= (3 * SZ + 4 * WSZ + 3 * SIDE) * 2;

  unsigned short* Hbf = (unsigned short*)d_out;
  float* D = (float*)d_out;  // overlays Hbf after QKV GEMM

  if (bigws) {
    unsigned short* Wbf = sC + SZ;              // ws tail
    unsigned short* side = Wbf + 4 * WSZ;
    unsigned short* gate = Hbf + SZ;            // d_out upper half (bf16)

    cvt_all<<<12288, 256, 0, stream>>>(H, Wq, Wk, Wv, Wg, Hbf, Wbf);
    // fused q/k/v/gate projection (side rows written in epilogue)
    gemm_a<<<dim3(32, 64), 256, 0, stream>>>(Hbf, Wbf, sA, sB, sC, gate, side);
    scan_seg<<<1024, 256, 0, stream>>>(sA, sB, sC, sA, sC,
                                       side, side + SIDE, side + 2 * SIDE,
                                       cq, ck, cv, D);
    prefix_D<<<dim3(16, 64), 256, 0, stream>>>(D, W0);
    corr_ln_gate<<<1024, 256, 0, stream>>>(sA, D, sC, sC, gate, gamma, beta);
    cvt_f2b<<<WSZ / 1024, 256, 0, stream>>>(Wo, sA);  // Wo bf16 (qc dead)
    gemm_w<<<dim3(16, 64), 256, 0, stream>>>(sC, sA, (float*)d_out);
  } else {
    unsigned short* Wbf = Hbf + SZ;             // d_out tail
    unsigned short* side = Wbf + 4 * WSZ;

    cvt_all<<<12288, 256, 0, stream>>>(H, Wq, Wk, Wv, Wg, Hbf, Wbf);
    gemm_a<<<dim3(24, 64), 256, 0, stream>>>(Hbf, Wbf, sA, sB, sC, nullptr, side);
    scan_seg<<<1024, 256, 0, stream>>>(sA, sB, sC, sA, sC,
                                       side, side + SIDE, side + 2 * SIDE,
                                       cq, ck, cv, D);
    gemm_gate<<<dim3(8, 64), 256, 0, stream>>>(H, Wbf + 3 * WSZ, sB);  // gate
    prefix_D<<<dim3(16, 64), 256, 0, stream>>>(D, W0);
    corr_ln_gate<<<1024, 256, 0, stream>>>(sA, D, sC, sC, sB, gamma, beta);
    cvt_f2b<<<WSZ / 1024, 256, 0, stream>>>(Wo, sA);
    gemm_w<<<dim3(16, 64), 256, 0, stream>>>(sC, sA, (float*)d_out);
  }
}